// Round 1
// baseline (2061.530 us; speedup 1.0000x reference)
//
#include <hip/hip_runtime.h>
#include <hip/hip_bf16.h>
#include <stdint.h>

#define HIDDEN 4096
#define INTER  14336
#define NSEL   4096

using short8 = __attribute__((ext_vector_type(8))) short;
using f32x4  = __attribute__((ext_vector_type(4))) float;

__device__ __forceinline__ uint16_t f2bf(float f) {
  uint32_t u = __float_as_uint(f);
  uint32_t r = (u + 0x7FFFu + ((u >> 16) & 1u)) >> 16;
  return (uint16_t)r;
}
__device__ __forceinline__ float bf2f(uint16_t h) {
  return __uint_as_float(((uint32_t)h) << 16);
}
__device__ __forceinline__ uint32_t pack2(float lo, float hi) {
  return (uint32_t)f2bf(lo) | ((uint32_t)f2bf(hi) << 16);
}

// ---- fp32 -> bf16 conversion, 8 elems/thread, exact-fit grid ----
__global__ void cvt_f32_bf16(const float* __restrict__ in, uint16_t* __restrict__ out) {
  size_t i = ((size_t)blockIdx.x * 256 + threadIdx.x) * 8;
  float4 a = *(const float4*)(in + i);
  float4 b = *(const float4*)(in + i + 4);
  uint4 v;
  v.x = pack2(a.x, a.y); v.y = pack2(a.z, a.w);
  v.z = pack2(b.x, b.y); v.w = pack2(b.z, b.w);
  *(uint4*)(out + i) = v;
}

// ---- gather selected tokens + cast to bf16: one block per token row ----
__global__ void gather_cast(const float* __restrict__ x, const int* __restrict__ idx,
                            uint16_t* __restrict__ xs) {
  const int n = blockIdx.x;
  const int t = threadIdx.x;
  const size_t s = (size_t)idx[n] * HIDDEN + (size_t)t * 16;
  const size_t d = (size_t)n * HIDDEN + (size_t)t * 16;
  const float4* sp = (const float4*)(x + s);
  float4 f0 = sp[0], f1 = sp[1], f2 = sp[2], f3 = sp[3];
  uint4 v0, v1;
  v0.x = pack2(f0.x, f0.y); v0.y = pack2(f0.z, f0.w);
  v0.z = pack2(f1.x, f1.y); v0.w = pack2(f1.z, f1.w);
  v1.x = pack2(f2.x, f2.y); v1.y = pack2(f2.z, f2.w);
  v1.z = pack2(f3.x, f3.y); v1.w = pack2(f3.z, f3.w);
  *(uint4*)(xs + d)     = v0;
  *(uint4*)(xs + d + 8) = v1;
}

__device__ __forceinline__ void gload16(const void* g, void* l) {
  __builtin_amdgcn_global_load_lds(
      (const __attribute__((address_space(1))) void*)g,
      (__attribute__((address_space(3))) void*)l, 16, 0, 0);
}

// ---- NT GEMM: C[M][N] = A[M][K] * B[N][K]^T, bf16 in, fp32 acc ----
// m97 structure: 128x128 tile, BK=64, 4 waves (2x2), 16x16x32 MFMA,
// global_load_lds width-16 staging, 2 barriers per K-step.
// EPI 0: store bf16 g.  EPI 1: h = silu(g)*acc, overwrite g buffer.
// EPI 2: out = acc * weight[row], fp32.
template<int EPI>
__global__ __launch_bounds__(256, 2) void gemm_nt(
    const uint16_t* __restrict__ A,
    const uint16_t* __restrict__ B,
    uint16_t* __restrict__ G,
    float* __restrict__ O,
    const float* __restrict__ Wt,
    int N, int K, int nbn)
{
  __shared__ uint16_t As[128 * 64];
  __shared__ uint16_t Bs[128 * 64];

  const int bm = blockIdx.x / nbn, bn = blockIdx.x % nbn;
  const int tid  = threadIdx.x;
  const int lane = tid & 63, w = tid >> 6;
  const int wr = w >> 1, wc = w & 1;
  const int lr = lane & 15, lg = lane >> 4;

  f32x4 acc[4][4];
#pragma unroll
  for (int m = 0; m < 4; ++m)
#pragma unroll
    for (int n = 0; n < 4; ++n)
#pragma unroll
      for (int j = 0; j < 4; ++j) acc[m][n][j] = 0.f;

  // staging: wave w stages 1024B chunks {4w..4w+3} of each tile.
  // chunk c covers rows 8c..8c+7 (row = 64 elems = 128 B).
  const int st_r = w * 32 + (lane >> 3);   // + i*8
  const int st_c = (lane & 7) * 8;
  const uint16_t* aP = A + (size_t)(bm * 128 + st_r) * K + st_c;
  const uint16_t* bP = B + (size_t)(bn * 128 + st_r) * K + st_c;

  const int nk = K >> 6;
  for (int kt = 0; kt < nk; ++kt) {
    __syncthreads();
    const size_t ko = (size_t)kt * 64;
#pragma unroll
    for (int i = 0; i < 4; ++i) {
      gload16(aP + (size_t)(i * 8) * K + ko, &As[(w * 4 + i) * 512]);
      gload16(bP + (size_t)(i * 8) * K + ko, &Bs[(w * 4 + i) * 512]);
    }
    __syncthreads();
#pragma unroll
    for (int ks = 0; ks < 2; ++ks) {
      short8 av[4], bv[4];
#pragma unroll
      for (int m = 0; m < 4; ++m)
        av[m] = *(const short8*)&As[(wr * 64 + m * 16 + lr) * 64 + ks * 32 + lg * 8];
#pragma unroll
      for (int n = 0; n < 4; ++n)
        bv[n] = *(const short8*)&Bs[(wc * 64 + n * 16 + lr) * 64 + ks * 32 + lg * 8];
#pragma unroll
      for (int m = 0; m < 4; ++m)
#pragma unroll
        for (int n = 0; n < 4; ++n)
          acc[m][n] = __builtin_amdgcn_mfma_f32_16x16x32_bf16(av[m], bv[n], acc[m][n], 0, 0, 0);
    }
  }

  // epilogue: C/D layout col = lane&15, row = (lane>>4)*4 + reg  [m89-verified]
  const int row0 = bm * 128 + wr * 64, col0 = bn * 128 + wc * 64;
#pragma unroll
  for (int m = 0; m < 4; ++m)
#pragma unroll
    for (int n = 0; n < 4; ++n) {
      const int c = col0 + n * 16 + lr;
      const int rb = row0 + m * 16 + lg * 4;
#pragma unroll
      for (int j = 0; j < 4; ++j) {
        const int r = rb + j;
        const float v = acc[m][n][j];
        if constexpr (EPI == 0) {
          G[(size_t)r * N + c] = f2bf(v);
        } else if constexpr (EPI == 1) {
          float gf = bf2f(G[(size_t)r * N + c]);
          float h = gf / (1.f + __expf(-gf)) * v;
          G[(size_t)r * N + c] = f2bf(h);
        } else {
          O[(size_t)r * N + c] = v * Wt[r];
        }
      }
    }
}

extern "C" void kernel_launch(void* const* d_in, const int* in_sizes, int n_in,
                              void* d_out, int out_size, void* d_ws, size_t ws_size,
                              hipStream_t stream) {
  const float* x   = (const float*)d_in[0];
  const float* Wg  = (const float*)d_in[1];
  const float* Wu  = (const float*)d_in[2];
  const float* Wd  = (const float*)d_in[3];
  const int*   top = (const int*)d_in[4];
  const float* wt  = (const float*)d_in[5];
  float* out = (float*)d_out;

  // ws layout (uint16 elems): xsel | W1 (Wg then Wd) | W2 (Wu) | g-then-h
  const size_t NE_X = (size_t)NSEL * HIDDEN;    // 16,777,216
  const size_t NE_W = (size_t)INTER * HIDDEN;   // 58,720,256
  if (ws_size < (NE_X + 3 * NE_W) * sizeof(uint16_t)) return;  // ~368 MB needed

  uint16_t* xs = (uint16_t*)d_ws;
  uint16_t* w1 = xs + NE_X;
  uint16_t* w2 = w1 + NE_W;
  uint16_t* gh = w2 + NE_W;

  const int WBLK = (int)(NE_W / (256 * 8));     // 28672, exact
  const int nbn1 = INTER / 128;                 // 112
  const int nbn2 = HIDDEN / 128;                // 32

  cvt_f32_bf16<<<WBLK, 256, 0, stream>>>(Wg, w1);
  cvt_f32_bf16<<<WBLK, 256, 0, stream>>>(Wu, w2);
  gather_cast<<<NSEL, 256, 0, stream>>>(x, top, xs);

  // gate: g = x_sel * Wg^T  -> gh (bf16)
  gemm_nt<0><<<(NSEL / 128) * nbn1, 256, 0, stream>>>(xs, w1, gh, nullptr, nullptr,
                                                      INTER, HIDDEN, nbn1);
  // Wd -> w1 (after gate GEMM consumed Wg; stream-ordered)
  cvt_f32_bf16<<<WBLK, 256, 0, stream>>>(Wd, w1);
  // up + SwiGLU: h = silu(g) * (x_sel * Wu^T) -> gh in place
  gemm_nt<1><<<(NSEL / 128) * nbn1, 256, 0, stream>>>(xs, w2, gh, nullptr, nullptr,
                                                      INTER, HIDDEN, nbn1);
  // down + routing weight: out = (h * Wd^T) * weight[:,None]
  gemm_nt<2><<<(NSEL / 128) * nbn2, 256, 0, stream>>>(gh, w1, nullptr, out, wt,
                                                      HIDDEN, INTER, nbn2);
}

// Round 2
// 1681.131 us; speedup vs baseline: 1.2263x; 1.2263x over previous
//
#include <hip/hip_runtime.h>
#include <hip/hip_bf16.h>
#include <stdint.h>

#define HIDDEN 4096
#define INTER  14336
#define NSEL   4096

using short8 = __attribute__((ext_vector_type(8))) short;
using f32x4  = __attribute__((ext_vector_type(4))) float;

__device__ __forceinline__ uint16_t f2bf(float f) {
  uint32_t u = __float_as_uint(f);
  uint32_t r = (u + 0x7FFFu + ((u >> 16) & 1u)) >> 16;
  return (uint16_t)r;
}
__device__ __forceinline__ float bf2f(uint16_t h) {
  return __uint_as_float(((uint32_t)h) << 16);
}
__device__ __forceinline__ uint32_t pack2(float lo, float hi) {
  return (uint32_t)f2bf(lo) | ((uint32_t)f2bf(hi) << 16);
}

// ---- fp32 -> bf16 conversion, 8 elems/thread ----
__global__ void cvt_f32_bf16(const float* __restrict__ in, uint16_t* __restrict__ out) {
  size_t i = ((size_t)blockIdx.x * 256 + threadIdx.x) * 8;
  float4 a = *(const float4*)(in + i);
  float4 b = *(const float4*)(in + i + 4);
  uint4 v;
  v.x = pack2(a.x, a.y); v.y = pack2(a.z, a.w);
  v.z = pack2(b.x, b.y); v.w = pack2(b.z, b.w);
  *(uint4*)(out + i) = v;
}

// ---- gather selected tokens + cast to bf16 ----
__global__ void gather_cast(const float* __restrict__ x, const int* __restrict__ idx,
                            uint16_t* __restrict__ xs) {
  const int n = blockIdx.x;
  const int t = threadIdx.x;
  const size_t s = (size_t)idx[n] * HIDDEN + (size_t)t * 16;
  const size_t d = (size_t)n * HIDDEN + (size_t)t * 16;
  const float4* sp = (const float4*)(x + s);
  float4 f0 = sp[0], f1 = sp[1], f2 = sp[2], f3 = sp[3];
  uint4 v0, v1;
  v0.x = pack2(f0.x, f0.y); v0.y = pack2(f0.z, f0.w);
  v0.z = pack2(f1.x, f1.y); v0.w = pack2(f1.z, f1.w);
  v1.x = pack2(f2.x, f2.y); v1.y = pack2(f2.z, f2.w);
  v1.z = pack2(f3.x, f3.y); v1.w = pack2(f3.z, f3.w);
  *(uint4*)(xs + d)     = v0;
  *(uint4*)(xs + d + 8) = v1;
}

__device__ __forceinline__ void gload16(const void* g, void* l) {
  __builtin_amdgcn_global_load_lds(
      (const __attribute__((address_space(1))) void*)g,
      (__attribute__((address_space(3))) void*)l, 16, 0, 0);
}

// ============================================================================
// NT GEMM, 256x256 tile, BK=32, 8 waves (2Mx4N), 512 threads.
// 4-slot LDS ring (4 x (A 16KB + B 16KB) = 128 KiB): tile t in slot t&3;
// during tile t we stage tile t+2 into slot (t+2)&3 (its last reader was
// tile t-2, already barrier-certified done). End-of-tile s_waitcnt vmcnt(4)
// certifies tile t+1 landed (counted, never 0 in steady state) + s_barrier.
// Raw s_barrier (NOT __syncthreads) so no vmcnt(0) drain is emitted.
// LDS swizzle: line = 2 rows x 32 cols = 128B; 16B-slot ^= (line&7).
// Staged via pre-inverse-swizzled GLOBAL source, linear gload_lds dest
// (rule 21); reads apply the same involution -> conflict-free ds_read_b128.
// EPI 0: store bf16 g. EPI 1: h = silu(g)*acc overwrite. EPI 2: out=acc*wt.
// ============================================================================
template<int EPI>
__global__ __launch_bounds__(512, 2) void gemm_nt(
    const uint16_t* __restrict__ A,
    const uint16_t* __restrict__ B,
    uint16_t* __restrict__ G,
    float* __restrict__ O,
    const float* __restrict__ Wt,
    int N, int K, int nbn)
{
  __shared__ __align__(16) uint16_t lds[4][2][8192];   // [slot][A/B][16KB]

  // T1: bijective XCD swizzle (grid % 8 == 0 for all three GEMMs)
  const int nwg = (int)gridDim.x;
  const int lid = ((int)blockIdx.x & 7) * (nwg >> 3) + ((int)blockIdx.x >> 3);
  const int bm = lid / nbn, bn = lid % nbn;

  const int tid  = (int)threadIdx.x;
  const int lane = tid & 63, w = tid >> 6;
  const int wm = w >> 2, wn = w & 3;          // wave tile: rows wm*128, cols wn*64
  const int lr = lane & 15, lg = lane >> 4;

  // fragment LDS offsets (u16 units), fixed across tiles (slot-relative)
  int offA[8], offB[4];
#pragma unroll
  for (int m = 0; m < 8; ++m) {
    const int r = wm * 128 + m * 16 + lr;
    offA[m] = (r >> 1) * 64 + ((((r & 1) << 2 | lg) ^ ((r >> 1) & 7)) * 8);
  }
#pragma unroll
  for (int n = 0; n < 4; ++n) {
    const int r = wn * 64 + n * 16 + lr;
    offB[n] = (r >> 1) * 64 + ((((r & 1) << 2 | lg) ^ ((r >> 1) & 7)) * 8);
  }

  // staging: thread t covers LDS-linear (line = i*64 + t/8, slot16 = t&7);
  // inverse-swizzled global source: su = (t&7) ^ (line&7) (line&7 == (t>>3)&7
  // for both rounds since round stride = 64 lines)
  const int su   = (tid & 7) ^ ((tid >> 3) & 7);
  const int sRow = 2 * (tid >> 3) + (su >> 2);
  const int sCol = (su & 3) * 8;
  const uint16_t* aSrc = A + (size_t)(bm * 256 + sRow) * K + sCol;
  const uint16_t* bSrc = B + (size_t)(bn * 256 + sRow) * K + sCol;
  const size_t rowStep = (size_t)128 * K;

#define STAGE_A(tt, s) do { \
    const uint16_t* _p = aSrc + (size_t)(tt) * 32; \
    gload16(_p,           &lds[s][0][tid * 8]); \
    gload16(_p + rowStep, &lds[s][0][4096 + tid * 8]); \
  } while (0)
#define STAGE_B(tt, s) do { \
    const uint16_t* _p = bSrc + (size_t)(tt) * 32; \
    gload16(_p,           &lds[s][1][tid * 8]); \
    gload16(_p + rowStep, &lds[s][1][4096 + tid * 8]); \
  } while (0)

  f32x4 acc[8][4];
#pragma unroll
  for (int m = 0; m < 8; ++m)
#pragma unroll
    for (int n = 0; n < 4; ++n)
#pragma unroll
      for (int j = 0; j < 4; ++j) acc[m][n][j] = 0.f;

  const int nk = K >> 5;

  // prologue: stage tiles 0,1; certify tile 0 (vmcnt(4) leaves tile 1 in flight)
  STAGE_A(0, 0); STAGE_B(0, 0);
  STAGE_A(1, 1); STAGE_B(1, 1);
  asm volatile("s_waitcnt vmcnt(4)" ::: "memory");
  __builtin_amdgcn_s_barrier();

  for (int t = 0; t < nk; ++t) {
    const int s  = t & 3;
    const int sn = (t + 2) & 3;
    const bool pre = (t + 2) < nk;
    const uint16_t* As = &lds[s][0][0];
    const uint16_t* Bs = &lds[s][1][0];

    short8 av[4], bv[4];
    // ---- phase 0: m-frags 0..3 ----
#pragma unroll
    for (int i = 0; i < 4; ++i) av[i] = *(const short8*)&As[offA[i]];
#pragma unroll
    for (int n = 0; n < 4; ++n) bv[n] = *(const short8*)&Bs[offB[n]];
    if (pre) STAGE_A(t + 2, sn);
    __builtin_amdgcn_s_barrier();
    __builtin_amdgcn_s_setprio(1);
#pragma unroll
    for (int i = 0; i < 4; ++i)
#pragma unroll
      for (int n = 0; n < 4; ++n)
        acc[i][n] = __builtin_amdgcn_mfma_f32_16x16x32_bf16(av[i], bv[n], acc[i][n], 0, 0, 0);
    __builtin_amdgcn_s_setprio(0);
    __builtin_amdgcn_s_barrier();

    // ---- phase 1: m-frags 4..7 (bv reused) ----
#pragma unroll
    for (int i = 0; i < 4; ++i) av[i] = *(const short8*)&As[offA[4 + i]];
    if (pre) STAGE_B(t + 2, sn);
    __builtin_amdgcn_s_barrier();
    __builtin_amdgcn_s_setprio(1);
#pragma unroll
    for (int i = 0; i < 4; ++i)
#pragma unroll
      for (int n = 0; n < 4; ++n)
        acc[4 + i][n] = __builtin_amdgcn_mfma_f32_16x16x32_bf16(av[i], bv[n], acc[4 + i][n], 0, 0, 0);
    __builtin_amdgcn_s_setprio(0);
    // counted wait: tile t+1 must be landed; t+2's 4 loads stay in flight
    if (pre) { asm volatile("s_waitcnt vmcnt(4)" ::: "memory"); }
    else     { asm volatile("s_waitcnt vmcnt(0)" ::: "memory"); }
    __builtin_amdgcn_s_barrier();
  }
#undef STAGE_A
#undef STAGE_B

  // epilogue: C/D layout col = lane&15, row = (lane>>4)*4 + reg [m89-verified]
  const int row0 = bm * 256 + wm * 128, col0 = bn * 256 + wn * 64;
#pragma unroll
  for (int m = 0; m < 8; ++m)
#pragma unroll
    for (int n = 0; n < 4; ++n) {
      const int c  = col0 + n * 16 + lr;
      const int rb = row0 + m * 16 + lg * 4;
#pragma unroll
      for (int j = 0; j < 4; ++j) {
        const int r = rb + j;
        const float v = acc[m][n][j];
        if constexpr (EPI == 0) {
          G[(size_t)r * N + c] = f2bf(v);
        } else if constexpr (EPI == 1) {
          float gf = bf2f(G[(size_t)r * N + c]);
          float h = gf / (1.f + __expf(-gf)) * v;
          G[(size_t)r * N + c] = f2bf(h);
        } else {
          O[(size_t)r * N + c] = v * Wt[r];
        }
      }
    }
}

extern "C" void kernel_launch(void* const* d_in, const int* in_sizes, int n_in,
                              void* d_out, int out_size, void* d_ws, size_t ws_size,
                              hipStream_t stream) {
  const float* x   = (const float*)d_in[0];
  const float* Wg  = (const float*)d_in[1];
  const float* Wu  = (const float*)d_in[2];
  const float* Wd  = (const float*)d_in[3];
  const int*   top = (const int*)d_in[4];
  const float* wt  = (const float*)d_in[5];
  float* out = (float*)d_out;

  const size_t NE_X = (size_t)NSEL * HIDDEN;
  const size_t NE_W = (size_t)INTER * HIDDEN;
  if (ws_size < (NE_X + 3 * NE_W) * sizeof(uint16_t)) return;

  uint16_t* xs = (uint16_t*)d_ws;
  uint16_t* w1 = xs + NE_X;
  uint16_t* w2 = w1 + NE_W;
  uint16_t* gh = w2 + NE_W;

  const int WBLK = (int)(NE_W / (256 * 8));
  const int nbn1 = INTER / 256;    // 56
  const int nbn2 = HIDDEN / 256;   // 16

  cvt_f32_bf16<<<WBLK, 256, 0, stream>>>(Wg, w1);
  cvt_f32_bf16<<<WBLK, 256, 0, stream>>>(Wu, w2);
  gather_cast<<<NSEL, 256, 0, stream>>>(x, top, xs);

  // gate: g = x_sel * Wg^T -> gh (bf16)
  gemm_nt<0><<<(NSEL / 256) * nbn1, 512, 0, stream>>>(xs, w1, gh, nullptr, nullptr,
                                                      INTER, HIDDEN, nbn1);
  // Wd -> w1 (after gate GEMM consumed Wg; stream-ordered)
  cvt_f32_bf16<<<WBLK, 256, 0, stream>>>(Wd, w1);
  // up + SwiGLU: h = silu(g) * (x_sel * Wu^T) -> gh in place
  gemm_nt<1><<<(NSEL / 256) * nbn1, 512, 0, stream>>>(xs, w2, gh, nullptr, nullptr,
                                                      INTER, HIDDEN, nbn1);
  // down + routing weight: out = (h * Wd^T) * weight[:,None]
  gemm_nt<2><<<(NSEL / 256) * nbn2, 512, 0, stream>>>(gh, w1, nullptr, out, wt,
                                                      HIDDEN, INTER, nbn2);
}

// Round 3
// 1674.684 us; speedup vs baseline: 1.2310x; 1.0038x over previous
//
#include <hip/hip_runtime.h>
#include <hip/hip_bf16.h>
#include <stdint.h>

#define HIDDEN 4096
#define INTER  14336
#define NSEL   4096

using short8 = __attribute__((ext_vector_type(8))) short;
using f32x4  = __attribute__((ext_vector_type(4))) float;

__device__ __forceinline__ uint16_t f2bf(float f) {
  uint32_t u = __float_as_uint(f);
  uint32_t r = (u + 0x7FFFu + ((u >> 16) & 1u)) >> 16;
  return (uint16_t)r;
}
__device__ __forceinline__ float bf2f(uint16_t h) {
  return __uint_as_float(((uint32_t)h) << 16);
}
__device__ __forceinline__ uint32_t pack2(float lo, float hi) {
  return (uint32_t)f2bf(lo) | ((uint32_t)f2bf(hi) << 16);
}

// ---- fp32 -> bf16 conversion, 8 elems/thread ----
__global__ void cvt_f32_bf16(const float* __restrict__ in, uint16_t* __restrict__ out) {
  size_t i = ((size_t)blockIdx.x * 256 + threadIdx.x) * 8;
  float4 a = *(const float4*)(in + i);
  float4 b = *(const float4*)(in + i + 4);
  uint4 v;
  v.x = pack2(a.x, a.y); v.y = pack2(a.z, a.w);
  v.z = pack2(b.x, b.y); v.w = pack2(b.z, b.w);
  *(uint4*)(out + i) = v;
}

// ---- gather selected tokens + cast to bf16 ----
__global__ void gather_cast(const float* __restrict__ x, const int* __restrict__ idx,
                            uint16_t* __restrict__ xs) {
  const int n = blockIdx.x;
  const int t = threadIdx.x;
  const size_t s = (size_t)idx[n] * HIDDEN + (size_t)t * 16;
  const size_t d = (size_t)n * HIDDEN + (size_t)t * 16;
  const float4* sp = (const float4*)(x + s);
  float4 f0 = sp[0], f1 = sp[1], f2 = sp[2], f3 = sp[3];
  uint4 v0, v1;
  v0.x = pack2(f0.x, f0.y); v0.y = pack2(f0.z, f0.w);
  v0.z = pack2(f1.x, f1.y); v0.w = pack2(f1.z, f1.w);
  v1.x = pack2(f2.x, f2.y); v1.y = pack2(f2.z, f2.w);
  v1.z = pack2(f3.x, f3.y); v1.w = pack2(f3.z, f3.w);
  *(uint4*)(xs + d)     = v0;
  *(uint4*)(xs + d + 8) = v1;
}

__device__ __forceinline__ void gload16(const void* g, void* l) {
  __builtin_amdgcn_global_load_lds(
      (const __attribute__((address_space(1))) void*)g,
      (__attribute__((address_space(3))) void*)l, 16, 0, 0);
}

// ============================================================================
// NT GEMM, 256x256 tile, BK=32, 8 waves (2Mx4N), 512 threads.
// 4-slot LDS ring (128 KiB). ONE barrier + one counted vmcnt per K-tile:
// waves free-run within the tile so one wave's ds_reads overlap another's
// MFMAs (no lockstep bursts). Stage t+3 during tile t (slot (t-1)&3, whose
// readers drained before the end-of-(t-1) barrier -> WAR safe). End-of-tile
// s_waitcnt vmcnt(8) certifies tile t+1 (t+2,t+3's 8 loads stay in flight).
// LDS swizzle (T2): line = 2 rows x 32 cols = 128B; 16B-slot ^= (line&7),
// applied via pre-inverse-swizzled global source + swizzled read offsets
// (gload_lds dest stays linear). Verified: bank conflicts = 0.
// T1: bijective XCD swizzle; bm-fastest so concurrent blocks per XCD share
// B-panels (2x 2MB, L2-resident) and refetch the small A instead of big B.
// EPI 0: store bf16 g. EPI 1: h = silu(g)*acc overwrite. EPI 2: out=acc*wt.
// ============================================================================
template<int EPI>
__global__ __launch_bounds__(512, 2) void gemm_nt(
    const uint16_t* __restrict__ A,
    const uint16_t* __restrict__ B,
    uint16_t* __restrict__ G,
    float* __restrict__ O,
    const float* __restrict__ Wt,
    int N, int K, int nbm)
{
  __shared__ __align__(16) uint16_t lds[4][2][8192];   // [slot][A/B][16KB]

  const int nwg = (int)gridDim.x;
  const int lid = ((int)blockIdx.x & 7) * (nwg >> 3) + ((int)blockIdx.x >> 3);
  const int bm = lid % nbm, bn = lid / nbm;

  const int tid  = (int)threadIdx.x;
  const int lane = tid & 63, w = tid >> 6;
  const int wm = w >> 2, wn = w & 3;          // wave tile: rows wm*128, cols wn*64
  const int lr = lane & 15, lg = lane >> 4;

  // fragment LDS offsets (u16 units), slot-relative, swizzled
  int offA[8], offB[4];
#pragma unroll
  for (int m = 0; m < 8; ++m) {
    const int r = wm * 128 + m * 16 + lr;
    offA[m] = (r >> 1) * 64 + ((((r & 1) << 2 | lg) ^ ((r >> 1) & 7)) * 8);
  }
#pragma unroll
  for (int n = 0; n < 4; ++n) {
    const int r = wn * 64 + n * 16 + lr;
    offB[n] = (r >> 1) * 64 + ((((r & 1) << 2 | lg) ^ ((r >> 1) & 7)) * 8);
  }

  // staging: inverse-swizzled global source, linear gload_lds dest (rule 21)
  const int su   = (tid & 7) ^ ((tid >> 3) & 7);
  const int sRow = 2 * (tid >> 3) + (su >> 2);
  const int sCol = (su & 3) * 8;
  const uint16_t* aSrc = A + (size_t)(bm * 256 + sRow) * K + sCol;
  const uint16_t* bSrc = B + (size_t)(bn * 256 + sRow) * K + sCol;
  const size_t rowStep = (size_t)128 * K;

#define STAGE_A(tt, s) do { \
    const uint16_t* _p = aSrc + (size_t)(tt) * 32; \
    gload16(_p,           &lds[s][0][tid * 8]); \
    gload16(_p + rowStep, &lds[s][0][4096 + tid * 8]); \
  } while (0)
#define STAGE_B(tt, s) do { \
    const uint16_t* _p = bSrc + (size_t)(tt) * 32; \
    gload16(_p,           &lds[s][1][tid * 8]); \
    gload16(_p + rowStep, &lds[s][1][4096 + tid * 8]); \
  } while (0)

  f32x4 acc[8][4];
#pragma unroll
  for (int m = 0; m < 8; ++m)
#pragma unroll
    for (int n = 0; n < 4; ++n)
#pragma unroll
      for (int j = 0; j < 4; ++j) acc[m][n][j] = 0.f;

  const int nk = K >> 5;

  // prologue: stage tiles 0,1,2; certify tile 0 (8 loads stay in flight)
  STAGE_A(0, 0); STAGE_B(0, 0);
  STAGE_A(1, 1); STAGE_B(1, 1);
  STAGE_A(2, 2); STAGE_B(2, 2);
  asm volatile("s_waitcnt vmcnt(8)" ::: "memory");
  __builtin_amdgcn_s_barrier();

  for (int t = 0; t < nk; ++t) {
    const int s = t & 3;
    const uint16_t* As = &lds[s][0][0];
    const uint16_t* Bs = &lds[s][1][0];

    if (t + 3 < nk) {
      const int sn = (t + 3) & 3;
      STAGE_A(t + 3, sn);
      STAGE_B(t + 3, sn);
    }

    // hoist all 12 ds_reads; compiler emits progressive lgkmcnt waits
    short8 av[4], av2[4], bv[4];
#pragma unroll
    for (int i = 0; i < 4; ++i) av[i]  = *(const short8*)&As[offA[i]];
#pragma unroll
    for (int n = 0; n < 4; ++n) bv[n]  = *(const short8*)&Bs[offB[n]];
#pragma unroll
    for (int i = 0; i < 4; ++i) av2[i] = *(const short8*)&As[offA[4 + i]];

    __builtin_amdgcn_s_setprio(1);
#pragma unroll
    for (int i = 0; i < 4; ++i)
#pragma unroll
      for (int n = 0; n < 4; ++n)
        acc[i][n] = __builtin_amdgcn_mfma_f32_16x16x32_bf16(av[i], bv[n], acc[i][n], 0, 0, 0);
#pragma unroll
    for (int i = 0; i < 4; ++i)
#pragma unroll
      for (int n = 0; n < 4; ++n)
        acc[4 + i][n] = __builtin_amdgcn_mfma_f32_16x16x32_bf16(av2[i], bv[n], acc[4 + i][n], 0, 0, 0);
    __builtin_amdgcn_s_setprio(0);

    // certify tile t+1; keep t+2/t+3's loads in flight (never drain mid-loop)
    if      (t + 3 < nk) { asm volatile("s_waitcnt vmcnt(8)" ::: "memory"); }
    else if (t + 2 < nk) { asm volatile("s_waitcnt vmcnt(4)" ::: "memory"); }
    else                 { asm volatile("s_waitcnt vmcnt(0)" ::: "memory"); }
    __builtin_amdgcn_s_barrier();
  }
#undef STAGE_A
#undef STAGE_B

  // epilogue: C/D layout col = lane&15, row = (lane>>4)*4 + reg [m89-verified]
  const int row0 = bm * 256 + wm * 128, col0 = bn * 256 + wn * 64;
#pragma unroll
  for (int m = 0; m < 8; ++m)
#pragma unroll
    for (int n = 0; n < 4; ++n) {
      const int c  = col0 + n * 16 + lr;
      const int rb = row0 + m * 16 + lg * 4;
#pragma unroll
      for (int j = 0; j < 4; ++j) {
        const int r = rb + j;
        const float v = acc[m][n][j];
        if constexpr (EPI == 0) {
          G[(size_t)r * N + c] = f2bf(v);
        } else if constexpr (EPI == 1) {
          float gf = bf2f(G[(size_t)r * N + c]);
          float h = gf / (1.f + __expf(-gf)) * v;
          G[(size_t)r * N + c] = f2bf(h);
        } else {
          O[(size_t)r * N + c] = v * Wt[r];
        }
      }
    }
}

extern "C" void kernel_launch(void* const* d_in, const int* in_sizes, int n_in,
                              void* d_out, int out_size, void* d_ws, size_t ws_size,
                              hipStream_t stream) {
  const float* x   = (const float*)d_in[0];
  const float* Wg  = (const float*)d_in[1];
  const float* Wu  = (const float*)d_in[2];
  const float* Wd  = (const float*)d_in[3];
  const int*   top = (const int*)d_in[4];
  const float* wt  = (const float*)d_in[5];
  float* out = (float*)d_out;

  const size_t NE_X = (size_t)NSEL * HIDDEN;
  const size_t NE_W = (size_t)INTER * HIDDEN;
  if (ws_size < (NE_X + 3 * NE_W) * sizeof(uint16_t)) return;

  uint16_t* xs = (uint16_t*)d_ws;
  uint16_t* w1 = xs + NE_X;
  uint16_t* w2 = w1 + NE_W;
  uint16_t* gh = w2 + NE_W;

  const int WBLK = (int)(NE_W / (256 * 8));
  const int nbm = NSEL / 256;      // 16
  const int nbn1 = INTER / 256;    // 56
  const int nbn2 = HIDDEN / 256;   // 16

  cvt_f32_bf16<<<WBLK, 256, 0, stream>>>(Wg, w1);
  cvt_f32_bf16<<<WBLK, 256, 0, stream>>>(Wu, w2);
  gather_cast<<<NSEL, 256, 0, stream>>>(x, top, xs);

  // gate: g = x_sel * Wg^T -> gh (bf16)
  gemm_nt<0><<<nbm * nbn1, 512, 0, stream>>>(xs, w1, gh, nullptr, nullptr,
                                             INTER, HIDDEN, nbm);
  // Wd -> w1 (after gate GEMM consumed Wg; stream-ordered)
  cvt_f32_bf16<<<WBLK, 256, 0, stream>>>(Wd, w1);
  // up + SwiGLU: h = silu(g) * (x_sel * Wu^T) -> gh in place
  gemm_nt<1><<<nbm * nbn1, 512, 0, stream>>>(xs, w2, gh, nullptr, nullptr,
                                             INTER, HIDDEN, nbm);
  // down + routing weight: out = (h * Wd^T) * weight[:,None]
  gemm_nt<2><<<nbm * nbn2, 512, 0, stream>>>(gh, w1, nullptr, out, wt,
                                             HIDDEN, INTER, nbm);
}